// Round 7
// baseline (223.421 us; speedup 1.0000x reference)
//
#include <hip/hip_runtime.h>
#include <hip/hip_bf16.h>

#define FH 240
#define FIT_IN 1600
#define NK 2048            // table knots per e
#define TLO -16.0f
#define TINVH 64.0f        // knots per unit S (h = 1/64)

typedef _Float16 h8 __attribute__((ext_vector_type(8)));
typedef float f4v __attribute__((ext_vector_type(4)));

__device__ __forceinline__ float fast_tanh(float x) {
    float e2 = __builtin_amdgcn_exp2f(x * 2.8853900817779268f);
    return 1.0f - 2.0f * __builtin_amdgcn_rcpf(e2 + 1.0f);
}

#define FMA_ROW(r, s) \
    acc[r][0] += (s) * b0.x; acc[r][1] += (s) * b0.y; \
    acc[r][2] += (s) * b0.z; acc[r][3] += (s) * b0.w; \
    acc[r][4] += (s) * b1.x; acc[r][5] += (s) * b1.y; \
    acc[r][6] += (s) * b1.z; acc[r][7] += (s) * b1.w;

// ---------------------------------------------------------------------------
// k_prep: blocks 0..63 build the embedding table; blocks 64..511 convert
// fit weights to f16 transposed WT[tp][n][k]. (unchanged — proven)
// ---------------------------------------------------------------------------
#define TOFF_W0   0
#define TOFF_B0   28
#define TOFF_B1   56
#define TOFF_B2   108
#define TOFF_W1   208
#define TOFF_W2   1508
#define TOFF_H0T  6708
#define TOFF_H1T  10008
#define TSMEM     16608

__global__ __launch_bounds__(256) void k_prep(
    const float* __restrict__ eW0, const float* __restrict__ eB0,
    const float* __restrict__ eW1, const float* __restrict__ eB1,
    const float* __restrict__ eW2, const float* __restrict__ eB2,
    float* __restrict__ T,
    const float* __restrict__ fW0, const float* __restrict__ fW1,
    const float* __restrict__ fW2,
    _Float16* __restrict__ W0T, _Float16* __restrict__ W1T,
    _Float16* __restrict__ W2T)
{
    __shared__ float sm[TSMEM];
    const int t = threadIdx.x;

    if (blockIdx.x >= 64) {
        const int bid0 = blockIdx.x - 64;
        const int total = 768000 + 115200 + 115200;
        for (int idx = bid0 * 256 + t; idx < total; idx += 448 * 256) {
            if (idx < 768000) {
                const int tp = idx / 384000, r = idx - tp * 384000;
                const int n = r / 1600, k = r - n * 1600;
                W0T[idx] = (_Float16)fW0[tp * 384000 + k * 240 + n];
            } else if (idx < 883200) {
                const int j = idx - 768000;
                const int tp = j / 57600, r = j - tp * 57600;
                const int n = r / 240, k = r - n * 240;
                W1T[j] = (_Float16)fW1[tp * 57600 + k * 240 + n];
            } else {
                const int j = idx - 883200;
                const int tp = j / 57600, r = j - tp * 57600;
                const int n = r / 240, k = r - n * 240;
                W2T[j] = (_Float16)fW2[tp * 57600 + k * 240 + n];
            }
        }
        return;
    }

    const int w    = t >> 6;
    const int lane = t & 63;
    const int mi   = lane & 7;
    const int gi   = lane >> 3;
    const int mrow = w * 32 + mi * 4;

    const int e  = blockIdx.x >> 4;
    const int k0 = (blockIdx.x & 15) * 128;

    for (int idx = t; idx < 1250; idx += 256) {
        int k = idx / 50, g = idx - k * 50;
        sm[TOFF_W1 + k * 52 + g] = eW1[e * 1250 + idx];
    }
    for (int idx = t; idx < 5000; idx += 256) {
        int k = idx / 100, r = idx - k * 100;
        int half = r / 50, g = r - half * 50;
        sm[TOFF_W2 + k * 104 + half * 52 + g] = eW2[e * 5000 + idx];
    }
    if (t < 25)       { sm[TOFF_W0 + t] = eW0[e * 25 + t]; sm[TOFF_B0 + t] = eB0[e * 25 + t]; }
    else if (t < 75)  { sm[TOFF_B1 + (t - 25)] = eB1[e * 50 + (t - 25)]; }
    else if (t < 175) { sm[TOFF_B2 + (t - 75)] = eB2[e * 100 + (t - 75)]; }
    __syncthreads();

    if (t < 128) {
        const float S = TLO + (float)(k0 + t) * (1.0f / TINVH);
        #pragma unroll
        for (int k = 0; k < 25; ++k)
            sm[TOFF_H0T + k * 132 + t] = fast_tanh(S * sm[TOFF_W0 + k] + sm[TOFF_B0 + k]);
    }
    __syncthreads();

    {
        float acc[4][8];
        #pragma unroll
        for (int r = 0; r < 4; ++r)
            #pragma unroll
            for (int c = 0; c < 8; ++c) acc[r][c] = 0.f;

        #pragma unroll 5
        for (int k = 0; k < 25; ++k) {
            const float4 av = *(const float4*)&sm[TOFF_H0T + k * 132 + mrow];
            const float4 b0 = *(const float4*)&sm[TOFF_W1 + k * 52 + gi * 8];
            const float4 b1 = *(const float4*)&sm[TOFF_W1 + k * 52 + gi * 8 + 4];
            FMA_ROW(0, av.x) FMA_ROW(1, av.y) FMA_ROW(2, av.z) FMA_ROW(3, av.w)
        }
        #pragma unroll
        for (int c = 0; c < 8; ++c) {
            const int g = gi * 8 + c;
            if (g < 50) {
                const int gm = (g < 25) ? g : g - 25;
                const float4 h0r = *(const float4*)&sm[TOFF_H0T + gm * 132 + mrow];
                const float bias = sm[TOFF_B1 + g];
                float4 o;
                o.x = fast_tanh(acc[0][c] + bias) + h0r.x;
                o.y = fast_tanh(acc[1][c] + bias) + h0r.y;
                o.z = fast_tanh(acc[2][c] + bias) + h0r.z;
                o.w = fast_tanh(acc[3][c] + bias) + h0r.w;
                *(float4*)&sm[TOFF_H1T + g * 132 + mrow] = o;
            }
        }
    }
    __syncthreads();

    for (int half = 0; half < 2; ++half) {
        float acc[4][8];
        #pragma unroll
        for (int r = 0; r < 4; ++r)
            #pragma unroll
            for (int c = 0; c < 8; ++c) acc[r][c] = 0.f;

        #pragma unroll 5
        for (int k = 0; k < 50; ++k) {
            const float4 av = *(const float4*)&sm[TOFF_H1T + k * 132 + mrow];
            const float4 b0 = *(const float4*)&sm[TOFF_W2 + k * 104 + half * 52 + gi * 8];
            const float4 b1 = *(const float4*)&sm[TOFF_W2 + k * 104 + half * 52 + gi * 8 + 4];
            FMA_ROW(0, av.x) FMA_ROW(1, av.y) FMA_ROW(2, av.z) FMA_ROW(3, av.w)
        }
        #pragma unroll
        for (int c = 0; c < 8; ++c) {
            const int g = gi * 8 + c;
            if (g < 50) {
                const float4 h1r = *(const float4*)&sm[TOFF_H1T + g * 132 + mrow];
                const float bias = sm[TOFF_B2 + half * 50 + g];
                float* out = T + ((size_t)e * NK + k0 + mrow) * 100 + half * 50 + g;
                out[0]   = fast_tanh(acc[0][c] + bias) + h1r.x;
                out[100] = fast_tanh(acc[1][c] + bias) + h1r.y;
                out[200] = fast_tanh(acc[2][c] + bias) + h1r.z;
                out[300] = fast_tanh(acc[3][c] + bias) + h1r.w;
            }
        }
    }
}

// ---------------------------------------------------------------------------
// k_xyz: per atom: gather+lerp G from table, reduce xyz[c][g], emit DR (f16).
// (unchanged — proven)
// ---------------------------------------------------------------------------
__global__ __launch_bounds__(256) void k_xyz(
    const float* __restrict__ Ri, const float* __restrict__ T,
    _Float16* __restrict__ DRh)
{
    __shared__ float4 sR[256];
    __shared__ float  sF[256];
    __shared__ int    sI[256];
    __shared__ float  sXYZ[400];

    const int t   = threadIdx.x;
    const int blk = blockIdx.x;          // 0..2047
    const int b   = blk >> 9;
    const int i   = (blk >> 8) & 1;
    const int n   = blk & 255;

    for (int idx = t; idx < 400; idx += 256) sXYZ[idx] = 0.f;

    {
        const int jj = t >> 7, m = t & 127;
        const size_t row = ((size_t)(b * 512 + i * 256 + n)) * 256 + jj * 128 + m;
        const float4 r = *(const float4*)(Ri + row * 4);
        sR[t] = r;
        float u = (r.x - TLO) * TINVH;
        int ii = (int)u;
        ii = (ii < 0) ? 0 : ((ii > NK - 2) ? NK - 2 : ii);
        sI[t] = ii;
        sF[t] = u - (float)ii;
    }
    __syncthreads();

    const int jj = t >> 7;
    const int g  = t & 127;
    if (g < 100) {
        const float* Te = T + ((size_t)(i * 2 + jj)) * NK * 100 + g;
        float a0 = 0.f, a1 = 0.f, a2 = 0.f, a3 = 0.f;
        #pragma unroll 4
        for (int m = 0; m < 128; ++m) {
            const int s = jj * 128 + m;
            const float4 R = sR[s];
            const float  f = sF[s];
            const float* p = Te + (size_t)sI[s] * 100;
            const float v0 = p[0], v1 = p[100];
            const float G = v0 + f * (v1 - v0);
            a0 += R.x * G; a1 += R.y * G; a2 += R.z * G; a3 += R.w * G;
        }
        atomicAdd(&sXYZ[g],       a0);
        atomicAdd(&sXYZ[100 + g], a1);
        atomicAdd(&sXYZ[200 + g], a2);
        atomicAdd(&sXYZ[300 + g], a3);
    }
    __syncthreads();

    const float inv = 1.0f / 65536.0f;
    _Float16* dr = DRh + (((size_t)i * 4 + b) * 256 + n) * FIT_IN;
    for (int q = t; q < 400; q += 256) {
        const int gg = q >> 2, h0 = (q & 3) * 4;
        ushort4 pk;
        _Float16* ph = (_Float16*)&pk;
        #pragma unroll
        for (int r = 0; r < 4; ++r) {
            const int h = h0 + r;
            const float v = (sXYZ[gg] * sXYZ[h] + sXYZ[100 + gg] * sXYZ[100 + h]
                           + sXYZ[200 + gg] * sXYZ[200 + h] + sXYZ[300 + gg] * sXYZ[300 + h]) * inv;
            ph[r] = (_Float16)v;
        }
        *(ushort4*)(dr + gg * 16 + h0) = pk;
    }
}

// ---------------------------------------------------------------------------
// k_fit0: layer-0 GEMM, FULL K, no k-split, no P. Grid (m=16, n=15) = 240
// blocks x 256 thr. Block (m,nt) computes h0[m*128..+127][nt*16..+15]:
//   - stage its OWN 16-row W0T slice (16x1600 f16 = 51.5KB) in LDS ONCE;
//   - A streams direct from L2/L3 (2-deep pipeline, R3-verified addressing);
//   - 100 MFMAs/wave; epilogue writes FINAL h0 = tanh(acc+b0) to hA (f32).
// Traffic: aggregate W-L3 ~6MB + A ~7MB (vs 192MB re-read in the 44us
// monolith — the measured L3-BW wall). blockIdx.x = m so the 15 n-siblings
// of an m-tile co-locate on one XCD (bid%8) -> A re-reads hit local L2.
// LDS stride 1608 halfs: 16 rows step 4 banks -> 2-way conflict (free).
// Layouts (verified): A[m=lane&15][k=quad*8+j], B[k=quad*8+j][n=lane&15],
// D[row=quad*4+reg][col=lane&15].
// ---------------------------------------------------------------------------
__global__ __launch_bounds__(256) void k_fit0(
    const _Float16* __restrict__ DRh, const _Float16* __restrict__ W0T,
    const float* __restrict__ fb0, float* __restrict__ hA)
{
    __shared__ _Float16 sW[16 * 1608];   // 51.5 KB

    const int t    = threadIdx.x;
    const int w    = t >> 6;             // 0..3
    const int lane = t & 63;
    const int ln   = lane & 15;
    const int quad = lane >> 4;

    const int m  = blockIdx.x;           // 0..15
    const int nt = blockIdx.y;           // 0..14
    const int r0 = m * 128;
    const int tp = m >> 3;
    const int n0 = nt * 16;

    // bulk stage W slice: rows n0..n0+15 (cols of h0), k = 0..1599
    const _Float16* Wb = W0T + ((size_t)tp * 240 + n0) * FIT_IN;
    for (int q = t; q < 6400; q += 256) {            // 400 uint2 per row
        const int row = q / 400, kq = (q - row * 400) * 4;
        *(uint2*)&sW[row * 1608 + kq] = *(const uint2*)(Wb + (size_t)row * FIT_IN + kq);
    }
    __syncthreads();

    // wave w owns rows rw..rw+31 (2 m-frags)
    const int rw = r0 + w * 32;
    const _Float16* A0 = DRh + (size_t)(rw + ln) * FIT_IN;
    const _Float16* A1 = A0 + (size_t)16 * FIT_IN;
    const int kq = quad * 8;

    f4v acc0 = (f4v)0.f, acc1 = (f4v)0.f;
    h8 a0c = *(const h8*)(A0 + kq);
    h8 a1c = *(const h8*)(A1 + kq);
    h8 a0n = *(const h8*)(A0 + 32 + kq);
    h8 a1n = *(const h8*)(A1 + 32 + kq);

    #pragma unroll 2
    for (int s = 0; s < 50; ++s) {
        h8 a0f, a1f;
        if (s + 2 < 50) {
            const int k2 = (s + 2) * 32 + kq;
            a0f = *(const h8*)(A0 + k2);
            a1f = *(const h8*)(A1 + k2);
        }
        const h8 bfr = *(const h8*)&sW[ln * 1608 + s * 32 + kq];
        acc0 = __builtin_amdgcn_mfma_f32_16x16x32_f16(a0c, bfr, acc0, 0, 0, 0);
        acc1 = __builtin_amdgcn_mfma_f32_16x16x32_f16(a1c, bfr, acc1, 0, 0, 0);
        a0c = a0n; a1c = a1n;
        a0n = a0f; a1n = a1f;
    }

    // epilogue: final h0 (no residual in layer 0)
    const int col  = n0 + ln;
    const float bias = fb0[tp * FH + col];
    #pragma unroll
    for (int r = 0; r < 4; ++r) {
        const int row0a = rw + quad * 4 + r;
        const int row1a = rw + 16 + quad * 4 + r;
        hA[(size_t)row0a * FH + col] = fast_tanh(acc0[r] + bias);
        hA[(size_t)row1a * FH + col] = fast_tanh(acc1[r] + bias);
    }
}

// ---------------------------------------------------------------------------
// k_fit_tail: 1024 blocks x 2 rows x 256 thr (16 waves/CU — vs R6's 5% occ).
// No P, no reduce: reads final h0 from hA, then
//   h1 = tanh(h0 @ W1 + b1) + h0 ; h2 = tanh(h1 @ W2 + b2) + h1 ;
//   out = h2 . W3 + b3
// Layers as f32-FMA dots: thread owns (row m, col c); W rows stream f16
// from (XCD-local) L2; h broadcasts from LDS. 3 barriers total.
// ---------------------------------------------------------------------------
__global__ __launch_bounds__(256) void k_fit_tail(
    const float* __restrict__ hA,
    const _Float16* __restrict__ W1T, const _Float16* __restrict__ W2T,
    const float* __restrict__ fb1, const float* __restrict__ fb2,
    const float* __restrict__ fW3, const float* __restrict__ fb3,
    float* __restrict__ out)
{
    __shared__ float h[2][2 * FH];       // ping-pong, rows contiguous

    const int t  = threadIdx.x;
    const int r0 = blockIdx.x * 2;       // 0..2046
    const int tp = r0 >> 10;

    for (int e = t; e < 2 * FH; e += 256)
        h[0][e] = hA[(size_t)r0 * FH + e];
    __syncthreads();

    for (int layer = 0; layer < 2; ++layer) {
        const _Float16* Wt = (layer == 0 ? W1T : W2T) + (size_t)tp * FH * FH;
        const float* Bs    = (layer == 0 ? fb1 : fb2) + tp * FH;
        const float* hin   = h[layer];
        float* hout        = h[layer ^ 1];

        #pragma unroll
        for (int half = 0; half < 2; ++half) {
            const int e = t + half * 256;
            if (e < 2 * FH) {
                const int m = (e >= FH) ? 1 : 0;
                const int c = e - m * FH;
                const float* hr = hin + m * FH;
                const _Float16* wr = Wt + (size_t)c * FH;
                float acc = 0.f;
                #pragma unroll 6
                for (int k = 0; k < FH; k += 8) {
                    const h8 wv8 = *(const h8*)(wr + k);
                    #pragma unroll
                    for (int j = 0; j < 8; ++j)
                        acc += hr[k + j] * (float)wv8[j];
                }
                hout[e] = fast_tanh(acc + Bs[c]) + hr[c];
            }
        }
        __syncthreads();
    }

    // out: waves 0,1 handle rows 0,1 (h2 lives in h[0])
    const int w = t >> 6, lane = t & 63;
    if (w < 2) {
        const float* h2 = h[0] + w * FH;
        const float* wv = fW3 + tp * FH;
        float s = 0.f;
        #pragma unroll
        for (int k = lane; k < FH; k += 64) s += h2[k] * wv[k];
        #pragma unroll
        for (int off = 32; off > 0; off >>= 1) s += __shfl_down(s, off);
        if (lane == 0) {
            const int gr = r0 + w;
            const int b = (gr >> 8) & 3, n = gr & 255;
            out[b * 512 + tp * 256 + n] = s + fb3[tp];
        }
    }
}

// ---------------------------------------------------------------------------
extern "C" void kernel_launch(void* const* d_in, const int* in_sizes, int n_in,
                              void* d_out, int out_size, void* d_ws, size_t ws_size,
                              hipStream_t stream)
{
    const float* Ri  = (const float*)d_in[0];
    const float* eW0 = (const float*)d_in[1];
    const float* eB0 = (const float*)d_in[2];
    const float* eW1 = (const float*)d_in[3];
    const float* eB1 = (const float*)d_in[4];
    const float* eW2 = (const float*)d_in[5];
    const float* eB2 = (const float*)d_in[6];
    const float* fW0 = (const float*)d_in[7];
    const float* fb0 = (const float*)d_in[8];
    const float* fW1 = (const float*)d_in[9];
    const float* fb1 = (const float*)d_in[10];
    const float* fW2 = (const float*)d_in[11];
    const float* fb2 = (const float*)d_in[12];
    const float* fW3 = (const float*)d_in[13];
    const float* fb3 = (const float*)d_in[14];

    // workspace layout (bytes)
    char* p = (char*)d_ws;
    float* T   = (float*)p;                 p += (size_t)4 * NK * 100 * 4;        // 3.28 MB
    _Float16* DRh = (_Float16*)p;           p += (size_t)2048 * FIT_IN * 2;       // 6.55 MB
    _Float16* W0T = (_Float16*)p;           p += (size_t)768000 * 2;              // 1.54 MB
    _Float16* W1T = (_Float16*)p;           p += (size_t)115200 * 2;
    _Float16* W2T = (_Float16*)p;           p += (size_t)115200 * 2;
    float* hA  = (float*)p;                 p += (size_t)2048 * FH * 4;           // 1.97 MB

    k_prep<<<dim3(512), dim3(256), 0, stream>>>(eW0, eB0, eW1, eB1, eW2, eB2, T,
                                                fW0, fW1, fW2, W0T, W1T, W2T);
    k_xyz<<<dim3(2048), dim3(256), 0, stream>>>(Ri, T, DRh);

    // layer 0: full-K GEMM, W-slice-resident blocks, writes final h0
    k_fit0<<<dim3(16, 15), dim3(256), 0, stream>>>(DRh, W0T, fb0, hA);

    // layers 1/2 + output dot, 2 rows/block (wide)
    k_fit_tail<<<dim3(1024), dim3(256), 0, stream>>>(hA, W1T, W2T, fb1, fb2,
                                                     fW3, fb3, (float*)d_out);
}

// Round 8
// 199.971 us; speedup vs baseline: 1.1173x; 1.1173x over previous
//
#include <hip/hip_runtime.h>
#include <hip/hip_bf16.h>

#define FH 240
#define FIT_IN 1600
#define NK 2048            // table knots per e
#define TLO -16.0f
#define TINVH 64.0f        // knots per unit S (h = 1/64)

typedef _Float16 h8 __attribute__((ext_vector_type(8)));
typedef float f4v __attribute__((ext_vector_type(4)));

__device__ __forceinline__ float fast_tanh(float x) {
    float e2 = __builtin_amdgcn_exp2f(x * 2.8853900817779268f);
    return 1.0f - 2.0f * __builtin_amdgcn_rcpf(e2 + 1.0f);
}

#define FMA_ROW(r, s) \
    acc[r][0] += (s) * b0.x; acc[r][1] += (s) * b0.y; \
    acc[r][2] += (s) * b0.z; acc[r][3] += (s) * b0.w; \
    acc[r][4] += (s) * b1.x; acc[r][5] += (s) * b1.y; \
    acc[r][6] += (s) * b1.z; acc[r][7] += (s) * b1.w;

// ---------------------------------------------------------------------------
// k_prep: blocks 0..63 build the embedding table; blocks 64..511 convert
// fit weights to f16 transposed WT[tp][n][k]. (unchanged — proven)
// ---------------------------------------------------------------------------
#define TOFF_W0   0
#define TOFF_B0   28
#define TOFF_B1   56
#define TOFF_B2   108
#define TOFF_W1   208
#define TOFF_W2   1508
#define TOFF_H0T  6708
#define TOFF_H1T  10008
#define TSMEM     16608

__global__ __launch_bounds__(256) void k_prep(
    const float* __restrict__ eW0, const float* __restrict__ eB0,
    const float* __restrict__ eW1, const float* __restrict__ eB1,
    const float* __restrict__ eW2, const float* __restrict__ eB2,
    float* __restrict__ T,
    const float* __restrict__ fW0, const float* __restrict__ fW1,
    const float* __restrict__ fW2,
    _Float16* __restrict__ W0T, _Float16* __restrict__ W1T,
    _Float16* __restrict__ W2T)
{
    __shared__ float sm[TSMEM];
    const int t = threadIdx.x;

    if (blockIdx.x >= 64) {
        const int bid0 = blockIdx.x - 64;
        const int total = 768000 + 115200 + 115200;
        for (int idx = bid0 * 256 + t; idx < total; idx += 448 * 256) {
            if (idx < 768000) {
                const int tp = idx / 384000, r = idx - tp * 384000;
                const int n = r / 1600, k = r - n * 1600;
                W0T[idx] = (_Float16)fW0[tp * 384000 + k * 240 + n];
            } else if (idx < 883200) {
                const int j = idx - 768000;
                const int tp = j / 57600, r = j - tp * 57600;
                const int n = r / 240, k = r - n * 240;
                W1T[j] = (_Float16)fW1[tp * 57600 + k * 240 + n];
            } else {
                const int j = idx - 883200;
                const int tp = j / 57600, r = j - tp * 57600;
                const int n = r / 240, k = r - n * 240;
                W2T[j] = (_Float16)fW2[tp * 57600 + k * 240 + n];
            }
        }
        return;
    }

    const int w    = t >> 6;
    const int lane = t & 63;
    const int mi   = lane & 7;
    const int gi   = lane >> 3;
    const int mrow = w * 32 + mi * 4;

    const int e  = blockIdx.x >> 4;
    const int k0 = (blockIdx.x & 15) * 128;

    for (int idx = t; idx < 1250; idx += 256) {
        int k = idx / 50, g = idx - k * 50;
        sm[TOFF_W1 + k * 52 + g] = eW1[e * 1250 + idx];
    }
    for (int idx = t; idx < 5000; idx += 256) {
        int k = idx / 100, r = idx - k * 100;
        int half = r / 50, g = r - half * 50;
        sm[TOFF_W2 + k * 104 + half * 52 + g] = eW2[e * 5000 + idx];
    }
    if (t < 25)       { sm[TOFF_W0 + t] = eW0[e * 25 + t]; sm[TOFF_B0 + t] = eB0[e * 25 + t]; }
    else if (t < 75)  { sm[TOFF_B1 + (t - 25)] = eB1[e * 50 + (t - 25)]; }
    else if (t < 175) { sm[TOFF_B2 + (t - 75)] = eB2[e * 100 + (t - 75)]; }
    __syncthreads();

    if (t < 128) {
        const float S = TLO + (float)(k0 + t) * (1.0f / TINVH);
        #pragma unroll
        for (int k = 0; k < 25; ++k)
            sm[TOFF_H0T + k * 132 + t] = fast_tanh(S * sm[TOFF_W0 + k] + sm[TOFF_B0 + k]);
    }
    __syncthreads();

    {
        float acc[4][8];
        #pragma unroll
        for (int r = 0; r < 4; ++r)
            #pragma unroll
            for (int c = 0; c < 8; ++c) acc[r][c] = 0.f;

        #pragma unroll 5
        for (int k = 0; k < 25; ++k) {
            const float4 av = *(const float4*)&sm[TOFF_H0T + k * 132 + mrow];
            const float4 b0 = *(const float4*)&sm[TOFF_W1 + k * 52 + gi * 8];
            const float4 b1 = *(const float4*)&sm[TOFF_W1 + k * 52 + gi * 8 + 4];
            FMA_ROW(0, av.x) FMA_ROW(1, av.y) FMA_ROW(2, av.z) FMA_ROW(3, av.w)
        }
        #pragma unroll
        for (int c = 0; c < 8; ++c) {
            const int g = gi * 8 + c;
            if (g < 50) {
                const int gm = (g < 25) ? g : g - 25;
                const float4 h0r = *(const float4*)&sm[TOFF_H0T + gm * 132 + mrow];
                const float bias = sm[TOFF_B1 + g];
                float4 o;
                o.x = fast_tanh(acc[0][c] + bias) + h0r.x;
                o.y = fast_tanh(acc[1][c] + bias) + h0r.y;
                o.z = fast_tanh(acc[2][c] + bias) + h0r.z;
                o.w = fast_tanh(acc[3][c] + bias) + h0r.w;
                *(float4*)&sm[TOFF_H1T + g * 132 + mrow] = o;
            }
        }
    }
    __syncthreads();

    for (int half = 0; half < 2; ++half) {
        float acc[4][8];
        #pragma unroll
        for (int r = 0; r < 4; ++r)
            #pragma unroll
            for (int c = 0; c < 8; ++c) acc[r][c] = 0.f;

        #pragma unroll 5
        for (int k = 0; k < 50; ++k) {
            const float4 av = *(const float4*)&sm[TOFF_H1T + k * 132 + mrow];
            const float4 b0 = *(const float4*)&sm[TOFF_W2 + k * 104 + half * 52 + gi * 8];
            const float4 b1 = *(const float4*)&sm[TOFF_W2 + k * 104 + half * 52 + gi * 8 + 4];
            FMA_ROW(0, av.x) FMA_ROW(1, av.y) FMA_ROW(2, av.z) FMA_ROW(3, av.w)
        }
        #pragma unroll
        for (int c = 0; c < 8; ++c) {
            const int g = gi * 8 + c;
            if (g < 50) {
                const float4 h1r = *(const float4*)&sm[TOFF_H1T + g * 132 + mrow];
                const float bias = sm[TOFF_B2 + half * 50 + g];
                float* out = T + ((size_t)e * NK + k0 + mrow) * 100 + half * 50 + g;
                out[0]   = fast_tanh(acc[0][c] + bias) + h1r.x;
                out[100] = fast_tanh(acc[1][c] + bias) + h1r.y;
                out[200] = fast_tanh(acc[2][c] + bias) + h1r.z;
                out[300] = fast_tanh(acc[3][c] + bias) + h1r.w;
            }
        }
    }
}

// ---------------------------------------------------------------------------
// k_xyz: per atom: gather+lerp G from table, reduce xyz[c][g], emit DR (f16).
// (unchanged — proven)
// ---------------------------------------------------------------------------
__global__ __launch_bounds__(256) void k_xyz(
    const float* __restrict__ Ri, const float* __restrict__ T,
    _Float16* __restrict__ DRh)
{
    __shared__ float4 sR[256];
    __shared__ float  sF[256];
    __shared__ int    sI[256];
    __shared__ float  sXYZ[400];

    const int t   = threadIdx.x;
    const int blk = blockIdx.x;          // 0..2047
    const int b   = blk >> 9;
    const int i   = (blk >> 8) & 1;
    const int n   = blk & 255;

    for (int idx = t; idx < 400; idx += 256) sXYZ[idx] = 0.f;

    {
        const int jj = t >> 7, m = t & 127;
        const size_t row = ((size_t)(b * 512 + i * 256 + n)) * 256 + jj * 128 + m;
        const float4 r = *(const float4*)(Ri + row * 4);
        sR[t] = r;
        float u = (r.x - TLO) * TINVH;
        int ii = (int)u;
        ii = (ii < 0) ? 0 : ((ii > NK - 2) ? NK - 2 : ii);
        sI[t] = ii;
        sF[t] = u - (float)ii;
    }
    __syncthreads();

    const int jj = t >> 7;
    const int g  = t & 127;
    if (g < 100) {
        const float* Te = T + ((size_t)(i * 2 + jj)) * NK * 100 + g;
        float a0 = 0.f, a1 = 0.f, a2 = 0.f, a3 = 0.f;
        #pragma unroll 4
        for (int m = 0; m < 128; ++m) {
            const int s = jj * 128 + m;
            const float4 R = sR[s];
            const float  f = sF[s];
            const float* p = Te + (size_t)sI[s] * 100;
            const float v0 = p[0], v1 = p[100];
            const float G = v0 + f * (v1 - v0);
            a0 += R.x * G; a1 += R.y * G; a2 += R.z * G; a3 += R.w * G;
        }
        atomicAdd(&sXYZ[g],       a0);
        atomicAdd(&sXYZ[100 + g], a1);
        atomicAdd(&sXYZ[200 + g], a2);
        atomicAdd(&sXYZ[300 + g], a3);
    }
    __syncthreads();

    const float inv = 1.0f / 65536.0f;
    _Float16* dr = DRh + (((size_t)i * 4 + b) * 256 + n) * FIT_IN;
    for (int q = t; q < 400; q += 256) {
        const int gg = q >> 2, h0 = (q & 3) * 4;
        ushort4 pk;
        _Float16* ph = (_Float16*)&pk;
        #pragma unroll
        for (int r = 0; r < 4; ++r) {
            const int h = h0 + r;
            const float v = (sXYZ[gg] * sXYZ[h] + sXYZ[100 + gg] * sXYZ[100 + h]
                           + sXYZ[200 + gg] * sXYZ[200 + h] + sXYZ[300 + gg] * sXYZ[300 + h]) * inv;
            ph[r] = (_Float16)v;
        }
        *(ushort4*)(dr + gg * 16 + h0) = pk;
    }
}

// ---------------------------------------------------------------------------
// k_fit0 v2: layer-0 GEMM, full K, no P. Grid (32 m x 15 n) = 480 blocks
// (~2 blocks/CU, 2 waves/SIMD — fixes R7's 1-wave/SIMD latency exposure),
// 64 rows/block, 256 thr; wave w owns 16 rows (one m-frag).
//   - stage the block's 16-row W0T slice (51.5 KB) in LDS ONCE (coalesced);
//   - A streams direct from XCD-local L2 (bid%8 = m%8 for all 15 n-siblings)
//     through a DEPTH-4 register prefetch ring (unroll-4 => static indexing);
//   - 50 MFMAs/wave; epilogue writes final h0 = tanh(acc+b0) to hA (f32).
// Verified layouts (R7 passing kernel): A[m=lane&15][k=quad*8+j],
// B[k=quad*8+j][n=lane&15], D[row=quad*4+reg][col=lane&15].
// ---------------------------------------------------------------------------
__global__ __launch_bounds__(256) void k_fit0(
    const _Float16* __restrict__ DRh, const _Float16* __restrict__ W0T,
    const float* __restrict__ fb0, float* __restrict__ hA)
{
    __shared__ _Float16 sW[16 * 1608];   // 51.5 KB

    const int t    = threadIdx.x;
    const int w    = t >> 6;             // 0..3
    const int lane = t & 63;
    const int ln   = lane & 15;
    const int quad = lane >> 4;

    const int m  = blockIdx.x;           // 0..31
    const int nt = blockIdx.y;           // 0..14
    const int r0 = m * 64;
    const int tp = m >> 4;
    const int n0 = nt * 16;

    // bulk stage W slice: rows n0..n0+15 (cols of h0), k = 0..1599
    const _Float16* Wb = W0T + ((size_t)tp * 240 + n0) * FIT_IN;
    for (int q = t; q < 6400; q += 256) {            // 400 uint2 per row
        const int row = q / 400, kq = (q - row * 400) * 4;
        *(uint2*)&sW[row * 1608 + kq] = *(const uint2*)(Wb + (size_t)row * FIT_IN + kq);
    }
    __syncthreads();

    // wave w owns rows rw..rw+15
    const int rw = r0 + w * 16;
    const _Float16* A0 = DRh + (size_t)(rw + ln) * FIT_IN;
    const int kq = quad * 8;

    f4v acc = (f4v)0.f;
    h8 p0 = *(const h8*)(A0 + 0 * 32 + kq);
    h8 p1 = *(const h8*)(A0 + 1 * 32 + kq);
    h8 p2 = *(const h8*)(A0 + 2 * 32 + kq);
    h8 p3 = *(const h8*)(A0 + 3 * 32 + kq);

    #pragma unroll 4
    for (int s = 0; s < 50; ++s) {
        h8 pf = p3;
        if (s + 4 < 50) pf = *(const h8*)(A0 + (s + 4) * 32 + kq);
        const h8 bfr = *(const h8*)&sW[ln * 1608 + s * 32 + kq];
        acc = __builtin_amdgcn_mfma_f32_16x16x32_f16(p0, bfr, acc, 0, 0, 0);
        p0 = p1; p1 = p2; p2 = p3; p3 = pf;
    }

    // epilogue: final h0 (no residual in layer 0)
    const int col  = n0 + ln;
    const float bias = fb0[tp * FH + col];
    #pragma unroll
    for (int r = 0; r < 4; ++r) {
        const int row = rw + quad * 4 + r;
        hA[(size_t)row * FH + col] = fast_tanh(acc[r] + bias);
    }
}

// ---------------------------------------------------------------------------
// k_fit_tail v2: R6's VERIFIED tail (bulk-staged 64-row W quarters, NaN-pad
// fix, single-owner hRes slots, per-wave frag ownership) with ONE change:
// phase A reads final h0 straight from hA (coalesced f32) instead of the
// 17-deep P reduce — that reduce was R6's 53.8us cost. 128 blocks x 16 rows.
// ---------------------------------------------------------------------------
__global__ __launch_bounds__(256) void k_fit_tail(
    const float* __restrict__ hA,
    const _Float16* __restrict__ W1T, const _Float16* __restrict__ W2T,
    const float* __restrict__ fb1, const float* __restrict__ fb2,
    const float* __restrict__ fW3, const float* __restrict__ fb3,
    float* __restrict__ out)
{
    __shared__ _Float16 sStage[64 * 248];     // 31.7 KB, W quarter [n_local][k]
    __shared__ _Float16 sAbuf[2][16 * 264];   // 2 x 8.4 KB, f16 A ping-pong
    __shared__ float    hRes[16 * 240];       // 15.4 KB, residual (single-owner)

    const int t    = threadIdx.x;
    const int w    = t >> 6;                  // 0..3
    const int lane = t & 63;
    const int ln   = lane & 15;
    const int quad = lane >> 4;
    const int r0   = blockIdx.x * 16;         // 0..2032
    const int tp   = r0 >> 10;

    // zero both sA buffers (covers k-pad cols 240..263)
    for (int q = t; q < 2 * 16 * 264; q += 256) ((_Float16*)sAbuf)[q] = (_Float16)0.f;
    // zero-fill sStage pad cols 240..247 for all 64 rows (R6 NaN fix)
    if (t < 128) {
        const int n = t >> 1, kq = 240 + (t & 1) * 4;
        *(uint2*)&sStage[n * 248 + kq] = make_uint2(0u, 0u);
    }

    // ---- phase A: load final h0 (coalesced) ----
    #pragma unroll
    for (int j = 0; j < 15; ++j) {
        const int e = t + j * 256;            // 0..3839 == 16*240 exactly
        const int m = e / 240, col = e - m * 240;
        const float v = hA[(size_t)r0 * FH + e];
        hRes[m * 240 + col] = v;
        sAbuf[0][m * 264 + col] = (_Float16)v;
    }

    // ---- layers 1,2: four 64-row bulk-staged quarters each ----
    for (int layer = 0; layer < 2; ++layer) {
        const _Float16* Wt = (layer == 0 ? W1T : W2T) + (size_t)tp * FH * FH;
        const float* Bias  = (layer == 0 ? fb1 : fb2) + tp * FH;
        const _Float16* inA = sAbuf[layer];
        _Float16* outA      = sAbuf[layer ^ 1];

        for (int p = 0; p < 4; ++p) {
            __syncthreads();                  // prev quarter's sStage reads done
            const int nrows = (p < 3) ? 64 : 48;
            for (int q = t; q < 64 * 60; q += 256) {   // 60 uint2 per row
                const int n = q / 60, kq = (q - n * 60) * 4;
                if (n < nrows)
                    *(uint2*)&sStage[n * 248 + kq] =
                        *(const uint2*)(Wt + (size_t)(p * 64 + n) * FH + kq);
            }
            __syncthreads();                  // stage visible

            const int f = p * 4 + w;          // frag this wave owns this quarter
            if (f < 15) {
                f4v acc = (f4v)0.f;
                #pragma unroll
                for (int s = 0; s < 8; ++s) { // K=240 padded to 256; pads are 0
                    const h8 afr = *(const h8*)&inA[ln * 264 + s * 32 + quad * 8];
                    const h8 bfr = *(const h8*)&sStage[(w * 16 + ln) * 248 + s * 32 + quad * 8];
                    acc = __builtin_amdgcn_mfma_f32_16x16x32_f16(afr, bfr, acc, 0, 0, 0);
                }
                const int col = f * 16 + ln;
                const float bias = Bias[col];
                #pragma unroll
                for (int r = 0; r < 4; ++r) {
                    const int m = quad * 4 + r;
                    const float v = fast_tanh(acc[r] + bias) + hRes[m * 240 + col];
                    hRes[m * 240 + col] = v;          // single-owner slot
                    outA[m * 264 + col] = (_Float16)v;
                }
            }
        }
    }
    __syncthreads();                          // h2 (hRes) complete

    // ---- out: per-wave row dot with W3 (h2 in hRes) ----
    const float* wv = fW3 + tp * FH;
    #pragma unroll
    for (int rr = 0; rr < 4; ++rr) {
        const int m = w * 4 + rr;
        float s = 0.f;
        for (int k = lane; k < FH; k += 64)
            s += hRes[m * 240 + k] * wv[k];
        #pragma unroll
        for (int off = 32; off > 0; off >>= 1) s += __shfl_down(s, off);
        if (lane == 0) {
            const int gr = r0 + m;
            const int b = (gr >> 8) & 3, n = gr & 255;
            out[b * 512 + tp * 256 + n] = s + fb3[tp];
        }
    }
}

// ---------------------------------------------------------------------------
extern "C" void kernel_launch(void* const* d_in, const int* in_sizes, int n_in,
                              void* d_out, int out_size, void* d_ws, size_t ws_size,
                              hipStream_t stream)
{
    const float* Ri  = (const float*)d_in[0];
    const float* eW0 = (const float*)d_in[1];
    const float* eB0 = (const float*)d_in[2];
    const float* eW1 = (const float*)d_in[3];
    const float* eB1 = (const float*)d_in[4];
    const float* eW2 = (const float*)d_in[5];
    const float* eB2 = (const float*)d_in[6];
    const float* fW0 = (const float*)d_in[7];
    const float* fb0 = (const float*)d_in[8];
    const float* fW1 = (const float*)d_in[9];
    const float* fb1 = (const float*)d_in[10];
    const float* fW2 = (const float*)d_in[11];
    const float* fb2 = (const float*)d_in[12];
    const float* fW3 = (const float*)d_in[13];
    const float* fb3 = (const float*)d_in[14];

    // workspace layout (bytes)
    char* p = (char*)d_ws;
    float* T   = (float*)p;                 p += (size_t)4 * NK * 100 * 4;        // 3.28 MB
    _Float16* DRh = (_Float16*)p;           p += (size_t)2048 * FIT_IN * 2;       // 6.55 MB
    _Float16* W0T = (_Float16*)p;           p += (size_t)768000 * 2;              // 1.54 MB
    _Float16* W1T = (_Float16*)p;           p += (size_t)115200 * 2;
    _Float16* W2T = (_Float16*)p;           p += (size_t)115200 * 2;
    float* hA  = (float*)p;                 p += (size_t)2048 * FH * 4;           // 1.97 MB

    k_prep<<<dim3(512), dim3(256), 0, stream>>>(eW0, eB0, eW1, eB1, eW2, eB2, T,
                                                fW0, fW1, fW2, W0T, W1T, W2T);
    k_xyz<<<dim3(2048), dim3(256), 0, stream>>>(Ri, T, DRh);

    // layer 0: full-K GEMM, W-slice-resident blocks, 2 blocks/CU, depth-4 ring
    k_fit0<<<dim3(32, 15), dim3(256), 0, stream>>>(DRh, W0T, fb0, hA);

    // layers 1/2 + output dot: R6 tail structure fed by hA (no P reduce)
    k_fit_tail<<<dim3(128), dim3(256), 0, stream>>>(hA, W1T, W2T, fb1, fb2,
                                                    fW3, fb3, (float*)d_out);
}

// Round 9
// 173.523 us; speedup vs baseline: 1.2876x; 1.1524x over previous
//
#include <hip/hip_runtime.h>
#include <hip/hip_bf16.h>

#define FH 240
#define FIT_IN 1600
#define NK 2048            // table knots per e
#define TLO -16.0f
#define TINVH 64.0f        // knots per unit S (h = 1/64)

typedef _Float16 h8 __attribute__((ext_vector_type(8)));
typedef float f4v __attribute__((ext_vector_type(4)));

__device__ __forceinline__ float fast_tanh(float x) {
    float e2 = __builtin_amdgcn_exp2f(x * 2.8853900817779268f);
    return 1.0f - 2.0f * __builtin_amdgcn_rcpf(e2 + 1.0f);
}

#define FMA_ROW(r, s) \
    acc[r][0] += (s) * b0.x; acc[r][1] += (s) * b0.y; \
    acc[r][2] += (s) * b0.z; acc[r][3] += (s) * b0.w; \
    acc[r][4] += (s) * b1.x; acc[r][5] += (s) * b1.y; \
    acc[r][6] += (s) * b1.z; acc[r][7] += (s) * b1.w;

// ---------------------------------------------------------------------------
// k_prep: blocks 0..63 build the embedding table; blocks 64..511 convert
// fit weights to f16 transposed WT[tp][n][k]. (unchanged — proven)
// ---------------------------------------------------------------------------
#define TOFF_W0   0
#define TOFF_B0   28
#define TOFF_B1   56
#define TOFF_B2   108
#define TOFF_W1   208
#define TOFF_W2   1508
#define TOFF_H0T  6708
#define TOFF_H1T  10008
#define TSMEM     16608

__global__ __launch_bounds__(256) void k_prep(
    const float* __restrict__ eW0, const float* __restrict__ eB0,
    const float* __restrict__ eW1, const float* __restrict__ eB1,
    const float* __restrict__ eW2, const float* __restrict__ eB2,
    float* __restrict__ T,
    const float* __restrict__ fW0, const float* __restrict__ fW1,
    const float* __restrict__ fW2,
    _Float16* __restrict__ W0T, _Float16* __restrict__ W1T,
    _Float16* __restrict__ W2T)
{
    __shared__ float sm[TSMEM];
    const int t = threadIdx.x;

    if (blockIdx.x >= 64) {
        const int bid0 = blockIdx.x - 64;
        const int total = 768000 + 115200 + 115200;
        for (int idx = bid0 * 256 + t; idx < total; idx += 448 * 256) {
            if (idx < 768000) {
                const int tp = idx / 384000, r = idx - tp * 384000;
                const int n = r / 1600, k = r - n * 1600;
                W0T[idx] = (_Float16)fW0[tp * 384000 + k * 240 + n];
            } else if (idx < 883200) {
                const int j = idx - 768000;
                const int tp = j / 57600, r = j - tp * 57600;
                const int n = r / 240, k = r - n * 240;
                W1T[j] = (_Float16)fW1[tp * 57600 + k * 240 + n];
            } else {
                const int j = idx - 883200;
                const int tp = j / 57600, r = j - tp * 57600;
                const int n = r / 240, k = r - n * 240;
                W2T[j] = (_Float16)fW2[tp * 57600 + k * 240 + n];
            }
        }
        return;
    }

    const int w    = t >> 6;
    const int lane = t & 63;
    const int mi   = lane & 7;
    const int gi   = lane >> 3;
    const int mrow = w * 32 + mi * 4;

    const int e  = blockIdx.x >> 4;
    const int k0 = (blockIdx.x & 15) * 128;

    for (int idx = t; idx < 1250; idx += 256) {
        int k = idx / 50, g = idx - k * 50;
        sm[TOFF_W1 + k * 52 + g] = eW1[e * 1250 + idx];
    }
    for (int idx = t; idx < 5000; idx += 256) {
        int k = idx / 100, r = idx - k * 100;
        int half = r / 50, g = r - half * 50;
        sm[TOFF_W2 + k * 104 + half * 52 + g] = eW2[e * 5000 + idx];
    }
    if (t < 25)       { sm[TOFF_W0 + t] = eW0[e * 25 + t]; sm[TOFF_B0 + t] = eB0[e * 25 + t]; }
    else if (t < 75)  { sm[TOFF_B1 + (t - 25)] = eB1[e * 50 + (t - 25)]; }
    else if (t < 175) { sm[TOFF_B2 + (t - 75)] = eB2[e * 100 + (t - 75)]; }
    __syncthreads();

    if (t < 128) {
        const float S = TLO + (float)(k0 + t) * (1.0f / TINVH);
        #pragma unroll
        for (int k = 0; k < 25; ++k)
            sm[TOFF_H0T + k * 132 + t] = fast_tanh(S * sm[TOFF_W0 + k] + sm[TOFF_B0 + k]);
    }
    __syncthreads();

    {
        float acc[4][8];
        #pragma unroll
        for (int r = 0; r < 4; ++r)
            #pragma unroll
            for (int c = 0; c < 8; ++c) acc[r][c] = 0.f;

        #pragma unroll 5
        for (int k = 0; k < 25; ++k) {
            const float4 av = *(const float4*)&sm[TOFF_H0T + k * 132 + mrow];
            const float4 b0 = *(const float4*)&sm[TOFF_W1 + k * 52 + gi * 8];
            const float4 b1 = *(const float4*)&sm[TOFF_W1 + k * 52 + gi * 8 + 4];
            FMA_ROW(0, av.x) FMA_ROW(1, av.y) FMA_ROW(2, av.z) FMA_ROW(3, av.w)
        }
        #pragma unroll
        for (int c = 0; c < 8; ++c) {
            const int g = gi * 8 + c;
            if (g < 50) {
                const int gm = (g < 25) ? g : g - 25;
                const float4 h0r = *(const float4*)&sm[TOFF_H0T + gm * 132 + mrow];
                const float bias = sm[TOFF_B1 + g];
                float4 o;
                o.x = fast_tanh(acc[0][c] + bias) + h0r.x;
                o.y = fast_tanh(acc[1][c] + bias) + h0r.y;
                o.z = fast_tanh(acc[2][c] + bias) + h0r.z;
                o.w = fast_tanh(acc[3][c] + bias) + h0r.w;
                *(float4*)&sm[TOFF_H1T + g * 132 + mrow] = o;
            }
        }
    }
    __syncthreads();

    for (int half = 0; half < 2; ++half) {
        float acc[4][8];
        #pragma unroll
        for (int r = 0; r < 4; ++r)
            #pragma unroll
            for (int c = 0; c < 8; ++c) acc[r][c] = 0.f;

        #pragma unroll 5
        for (int k = 0; k < 50; ++k) {
            const float4 av = *(const float4*)&sm[TOFF_H1T + k * 132 + mrow];
            const float4 b0 = *(const float4*)&sm[TOFF_W2 + k * 104 + half * 52 + gi * 8];
            const float4 b1 = *(const float4*)&sm[TOFF_W2 + k * 104 + half * 52 + gi * 8 + 4];
            FMA_ROW(0, av.x) FMA_ROW(1, av.y) FMA_ROW(2, av.z) FMA_ROW(3, av.w)
        }
        #pragma unroll
        for (int c = 0; c < 8; ++c) {
            const int g = gi * 8 + c;
            if (g < 50) {
                const float4 h1r = *(const float4*)&sm[TOFF_H1T + g * 132 + mrow];
                const float bias = sm[TOFF_B2 + half * 50 + g];
                float* out = T + ((size_t)e * NK + k0 + mrow) * 100 + half * 50 + g;
                out[0]   = fast_tanh(acc[0][c] + bias) + h1r.x;
                out[100] = fast_tanh(acc[1][c] + bias) + h1r.y;
                out[200] = fast_tanh(acc[2][c] + bias) + h1r.z;
                out[300] = fast_tanh(acc[3][c] + bias) + h1r.w;
            }
        }
    }
}

// ---------------------------------------------------------------------------
// k_xyz: per atom: gather+lerp G from table, reduce xyz[c][g], emit DR (f16).
// (unchanged — proven)
// ---------------------------------------------------------------------------
__global__ __launch_bounds__(256) void k_xyz(
    const float* __restrict__ Ri, const float* __restrict__ T,
    _Float16* __restrict__ DRh)
{
    __shared__ float4 sR[256];
    __shared__ float  sF[256];
    __shared__ int    sI[256];
    __shared__ float  sXYZ[400];

    const int t   = threadIdx.x;
    const int blk = blockIdx.x;          // 0..2047
    const int b   = blk >> 9;
    const int i   = (blk >> 8) & 1;
    const int n   = blk & 255;

    for (int idx = t; idx < 400; idx += 256) sXYZ[idx] = 0.f;

    {
        const int jj = t >> 7, m = t & 127;
        const size_t row = ((size_t)(b * 512 + i * 256 + n)) * 256 + jj * 128 + m;
        const float4 r = *(const float4*)(Ri + row * 4);
        sR[t] = r;
        float u = (r.x - TLO) * TINVH;
        int ii = (int)u;
        ii = (ii < 0) ? 0 : ((ii > NK - 2) ? NK - 2 : ii);
        sI[t] = ii;
        sF[t] = u - (float)ii;
    }
    __syncthreads();

    const int jj = t >> 7;
    const int g  = t & 127;
    if (g < 100) {
        const float* Te = T + ((size_t)(i * 2 + jj)) * NK * 100 + g;
        float a0 = 0.f, a1 = 0.f, a2 = 0.f, a3 = 0.f;
        #pragma unroll 4
        for (int m = 0; m < 128; ++m) {
            const int s = jj * 128 + m;
            const float4 R = sR[s];
            const float  f = sF[s];
            const float* p = Te + (size_t)sI[s] * 100;
            const float v0 = p[0], v1 = p[100];
            const float G = v0 + f * (v1 - v0);
            a0 += R.x * G; a1 += R.y * G; a2 += R.z * G; a3 += R.w * G;
        }
        atomicAdd(&sXYZ[g],       a0);
        atomicAdd(&sXYZ[100 + g], a1);
        atomicAdd(&sXYZ[200 + g], a2);
        atomicAdd(&sXYZ[300 + g], a3);
    }
    __syncthreads();

    const float inv = 1.0f / 65536.0f;
    _Float16* dr = DRh + (((size_t)i * 4 + b) * 256 + n) * FIT_IN;
    for (int q = t; q < 400; q += 256) {
        const int gg = q >> 2, h0 = (q & 3) * 4;
        ushort4 pk;
        _Float16* ph = (_Float16*)&pk;
        #pragma unroll
        for (int r = 0; r < 4; ++r) {
            const int h = h0 + r;
            const float v = (sXYZ[gg] * sXYZ[h] + sXYZ[100 + gg] * sXYZ[100 + h]
                           + sXYZ[200 + gg] * sXYZ[200 + h] + sXYZ[300 + gg] * sXYZ[300 + h]) * inv;
            ph[r] = (_Float16)v;
        }
        *(ushort4*)(dr + gg * 16 + h0) = pk;
    }
}

// ---------------------------------------------------------------------------
// k_fit: R3's verified monolith (passed @ 172.9us, fit = 44us) with ONE
// change: the layer-0 register pipeline is deepened from 2 to 8 steps
// (24 loads in flight/thread vs 6). Slot indexing is STATIC: 56-trip loop
// unrolled by 8, consume slot (s&7), then prefetch (s+8) into the same slot;
// uniform guards keep loads in-bounds and MFMAs off the s>=50 tail.
// 256 blocks x 512 threads, 8 rows/block; layers 1/2 and epilogues are
// byte-identical to R3.
// MFMA layouts (verified): A[m=lane&15][k=quad*8+j], B[k=quad*8+j][n=lane&15],
// D[row=quad*4+reg][col=lane&15].
// ---------------------------------------------------------------------------
__global__ __launch_bounds__(512) void k_fit(
    const _Float16* __restrict__ DRh,
    const _Float16* __restrict__ W0T, const _Float16* __restrict__ W1T,
    const _Float16* __restrict__ W2T,
    const float* __restrict__ fb0, const float* __restrict__ fb1,
    const float* __restrict__ fb2, const float* __restrict__ fW3,
    const float* __restrict__ fb3, float* __restrict__ out)
{
    __shared__ _Float16 sA[16 * 264];      // h f16 operand, k padded to 256 (zeros)
    __shared__ float    hRes[2][8 * 240];  // f32 h ping-pong (residual)

    const int t    = threadIdx.x;
    const int w    = t >> 6;               // 0..7
    const int lane = t & 63;
    const int ln   = lane & 15;
    const int quad = lane >> 4;
    const int r0   = blockIdx.x * 8;       // 0..2040
    const int tp   = r0 >> 10;
    const int nf0  = w * 2;
    const int nfr  = (w < 7) ? 2 : 1;      // 15 n-frags over 8 waves

    // zero sA (covers rows 8..15 and k-pad cols 240..263)
    for (int q = t; q < 16 * 264; q += 512) sA[q] = (_Float16)0.f;

    // ---------------- layer 0: K=1600, 50 k-steps, depth-8 reg ring ---------
    f4v acc[2];
    acc[0] = (f4v)0.f; acc[1] = (f4v)0.f;
    {
        // A: rows 8..15 of the MFMA M-dim alias rows 0..7 (discarded in D).
        const _Float16* Arow = DRh + (size_t)(r0 + (ln & 7)) * FIT_IN;
        const _Float16* W0b  = W0T + (size_t)tp * 240 * FIT_IN;
        const _Float16* Bp0  = W0b + (size_t)(nf0 * 16 + ln) * FIT_IN;
        const _Float16* Bp1  = W0b + (size_t)(((nfr > 1) ? nf0 + 1 : nf0) * 16 + ln) * FIT_IN;
        const int kq = quad * 8;

        h8 aR[8], b0R[8], b1R[8];
        #pragma unroll
        for (int j = 0; j < 8; ++j) {           // prologue: fill all 8 slots
            aR[j]  = *(const h8*)(Arow + j * 32 + kq);
            b0R[j] = *(const h8*)(Bp0 + j * 32 + kq);
            b1R[j] = *(const h8*)(Bp1 + j * 32 + kq);
        }

        #pragma unroll 8
        for (int s = 0; s < 56; ++s) {          // 56 = 7*8: slot idx static
            if (s < 50) {
                acc[0] = __builtin_amdgcn_mfma_f32_16x16x32_f16(aR[s & 7], b0R[s & 7], acc[0], 0, 0, 0);
                acc[1] = __builtin_amdgcn_mfma_f32_16x16x32_f16(aR[s & 7], b1R[s & 7], acc[1], 0, 0, 0);
            }
            if (s + 8 < 50) {
                const int k8 = (s + 8) * 32 + kq;
                aR[s & 7]  = *(const h8*)(Arow + k8);
                b0R[s & 7] = *(const h8*)(Bp0 + k8);
                b1R[s & 7] = *(const h8*)(Bp1 + k8);
            }
        }
    }
    // epilogue 0: acc -> h0 (valid rows live in quads 0,1)
    {
        const float* B0 = fb0 + tp * FH;
        #pragma unroll
        for (int nf = 0; nf < 2; ++nf) {
            if (nf < nfr && quad < 2) {
                const int col = (nf0 + nf) * 16 + ln;
                const float bias = B0[col];
                #pragma unroll
                for (int r = 0; r < 4; ++r) {
                    const int m = quad * 4 + r;
                    const float v = fast_tanh(acc[nf][r] + bias);
                    hRes[0][m * 240 + col] = v;
                    sA[m * 264 + col] = (_Float16)v;
                }
            }
        }
    }
    __syncthreads();

    // ---------------- layers 1,2: K=240 (pad 256), 8 k-steps ----------------
    for (int layer = 0; layer < 2; ++layer) {
        const _Float16* Wt = (layer == 0 ? W1T : W2T) + (size_t)tp * FH * FH;
        const float* Bias  = (layer == 0 ? fb1 : fb2) + tp * FH;
        const float* res   = hRes[layer];
        float* outb        = hRes[layer ^ 1];

        const _Float16* Bq0 = Wt + (size_t)(nf0 * 16 + ln) * FH;
        const _Float16* Bq1 = Wt + (size_t)(((nfr > 1) ? nf0 + 1 : nf0) * 16 + ln) * FH;
        const int kq = quad * 8;
        // NOTE: step 7's k=224..255 B-loads run past row end into the next
        // row/array (mapped ws memory); sA k-columns >=240 are zero, so the
        // garbage contributes 0 to the MFMA.

        f4v a2[2];
        a2[0] = (f4v)0.f; a2[1] = (f4v)0.f;

        h8 b0_c = *(const h8*)(Bq0 + kq);
        h8 b1_c = *(const h8*)(Bq1 + kq);
        #pragma unroll
        for (int s = 0; s < 8; ++s) {
            h8 b0_n, b1_n;
            if (s + 1 < 8) {
                const int k1 = (s + 1) * 32 + kq;
                b0_n = *(const h8*)(Bq0 + k1);
                b1_n = *(const h8*)(Bq1 + k1);
            }
            const h8 afr = *(const h8*)&sA[ln * 264 + s * 32 + kq];
            a2[0] = __builtin_amdgcn_mfma_f32_16x16x32_f16(afr, b0_c, a2[0], 0, 0, 0);
            a2[1] = __builtin_amdgcn_mfma_f32_16x16x32_f16(afr, b1_c, a2[1], 0, 0, 0);
            b0_c = b0_n;  b1_c = b1_n;
        }
        __syncthreads();    // all sA reads drained before epilogue rewrites sA
        #pragma unroll
        for (int nf = 0; nf < 2; ++nf) {
            if (nf < nfr && quad < 2) {
                const int col = (nf0 + nf) * 16 + ln;
                const float bias = Bias[col];
                #pragma unroll
                for (int r = 0; r < 4; ++r) {
                    const int m = quad * 4 + r;
                    const float v = fast_tanh(a2[nf][r] + bias) + res[m * 240 + col];
                    outb[m * 240 + col] = v;
                    if (layer == 0) sA[m * 264 + col] = (_Float16)v;
                }
            }
        }
        __syncthreads();    // outb/sA visible before next layer / out phase
    }

    // ---------------- out: row w per wave, h2 in hRes[0] ----------------
    {
        const float* h2 = hRes[0];
        const float* wv = fW3 + tp * FH;
        const int m = w;
        float s = 0.f;
        #pragma unroll
        for (int k = lane; k < FH; k += 64) s += h2[m * 240 + k] * wv[k];
        #pragma unroll
        for (int off = 32; off > 0; off >>= 1) s += __shfl_down(s, off);
        if (lane == 0) {
            const int gr = r0 + m;
            const int rem = gr & 1023;
            const int b = rem >> 8, n = rem & 255;
            out[b * 512 + tp * 256 + n] = s + fb3[tp];
        }
    }
}

// ---------------------------------------------------------------------------
extern "C" void kernel_launch(void* const* d_in, const int* in_sizes, int n_in,
                              void* d_out, int out_size, void* d_ws, size_t ws_size,
                              hipStream_t stream)
{
    const float* Ri  = (const float*)d_in[0];
    const float* eW0 = (const float*)d_in[1];
    const float* eB0 = (const float*)d_in[2];
    const float* eW1 = (const float*)d_in[3];
    const float* eB1 = (const float*)d_in[4];
    const float* eW2 = (const float*)d_in[5];
    const float* eB2 = (const float*)d_in[6];
    const float* fW0 = (const float*)d_in[7];
    const float* fb0 = (const float*)d_in[8];
    const float* fW1 = (const float*)d_in[9];
    const float* fb1 = (const float*)d_in[10];
    const float* fW2 = (const float*)d_in[11];
    const float* fb2 = (const float*)d_in[12];
    const float* fW3 = (const float*)d_in[13];
    const float* fb3 = (const float*)d_in[14];

    // workspace layout (bytes)
    char* p = (char*)d_ws;
    float* T   = (float*)p;                 p += (size_t)4 * NK * 100 * 4;        // 3.28 MB
    _Float16* DRh = (_Float16*)p;           p += (size_t)2048 * FIT_IN * 2;       // 6.55 MB
    _Float16* W0T = (_Float16*)p;           p += (size_t)768000 * 2;              // 1.54 MB
    _Float16* W1T = (_Float16*)p;           p += (size_t)115200 * 2;
    _Float16* W2T = (_Float16*)p;           p += (size_t)115200 * 2;

    k_prep<<<dim3(512), dim3(256), 0, stream>>>(eW0, eB0, eW1, eB1, eW2, eB2, T,
                                                fW0, fW1, fW2, W0T, W1T, W2T);
    k_xyz<<<dim3(2048), dim3(256), 0, stream>>>(Ri, T, DRh);
    k_fit<<<dim3(256), dim3(512), 0, stream>>>(DRh, W0T, W1T, W2T,
                                               fb0, fb1, fb2, fW3, fb3,
                                               (float*)d_out);
}